// Round 8
// baseline (172.965 us; speedup 1.0000x reference)
//
#include <hip/hip_runtime.h>

#define V 32
#define B 128
#define P 256
#define J 75
#define NF 32
#define S2 25
#define N1 500                                  // fc1 neurons

// ---------------------------------------------------------------------------
// Kernel 1: transform + SLayer.  Phase 2 register-tiled: 8 point-parts x
// 25 threads x 3 centers -> each 16B LDS read feeds 12 FMA + 3 exp
// (3x less LDS traffic than 1 center/thread).  Also zeroes acc[500*128].
// ---------------------------------------------------------------------------
__global__ __launch_bounds__(256) void slayer_kernel(
    const float* __restrict__ births,
    const float* __restrict__ lifetimes,
    const int* __restrict__ mask,
    const float* __restrict__ centers,
    const float* __restrict__ sharpness,
    float* __restrict__ z,                     // [V*B, J]
    float* __restrict__ acc_out)               // [N1*B] zeroed here
{
    const int vb = blockIdx.x;                 // v*B + b
    const int v  = vb >> 7;
    const int tid = threadIdx.x;
    const int lane = tid & 63;

    // zero fc1 accumulator: 64000 floats over 4096 blocks -> 16 each
    {
        const int base = vb * 16;
        if (tid < 16 && base + tid < N1 * B) acc_out[base + tid] = 0.f;
    }

    __shared__ float4 pts[P];
    __shared__ int cnt;
    __shared__ float part[8 * J];

    if (tid == 0) cnt = 0;
    __syncthreads();

    const float inv = 0.70710678118654752f;
    {
        const int gi = vb * P + tid;
        float b0 = births[gi];
        float l0 = lifetimes[gi];
        int   m  = mask[gi];
        float d  = b0 + l0 + 0.01f;
        float x  = (b0 + d) * inv;
        float y  = (d - b0) * inv;
        if (y <= 0.1f) y = __logf(y * 10.0f) * 0.1f + 0.1f;

        bool keep = (m != 0);
        unsigned long long bal = __ballot(keep);
        unsigned long long lt  = (1ull << lane) - 1ull;
        int prefix = __popcll(bal & lt);
        int total  = __popcll(bal);
        int base = 0;
        if (lane == 0) base = atomicAdd(&cnt, total);
        base = __shfl(base, 0, 64);
        if (keep) pts[base + prefix] = make_float4(x, y, x * x, y * y);
    }
    __syncthreads();

    const int n = cnt;
    const int pid = tid >> 5;                  // 0..7 point-part
    const int t32 = tid & 31;
    if (t32 < 25) {
        const int j0 = t32 * 3;                // 3 centers per thread
        float k0[3], k1[3], k2[3], k3[3], kc[3];
        #pragma unroll
        for (int c = 0; c < 3; ++c) {
            const int cj = (v * J + j0 + c) * 2;
            float cx = centers[cj + 0];
            float cy = centers[cj + 1];
            float sx = sharpness[cj + 0];
            float sy = sharpness[cj + 1];
            float s2x = sx * sx, s2y = sy * sy;
            k0[c] = -s2x;
            k1[c] = -s2y;
            k2[c] = 2.0f * s2x * cx;
            k3[c] = 2.0f * s2y * cy;
            kc[c] = -(s2x * cx * cx + s2y * cy * cy);
        }
        float a0 = 0.f, a1 = 0.f, a2 = 0.f;
        const int p0 = (n * pid) >> 3;
        const int p1 = (n * (pid + 1)) >> 3;
        #pragma unroll 2
        for (int p = p0; p < p1; ++p) {
            float4 a = pts[p];
            float d0 = fmaf(k0[0], a.z, kc[0]);
            d0 = fmaf(k1[0], a.w, d0); d0 = fmaf(k2[0], a.x, d0); d0 = fmaf(k3[0], a.y, d0);
            float d1 = fmaf(k0[1], a.z, kc[1]);
            d1 = fmaf(k1[1], a.w, d1); d1 = fmaf(k2[1], a.x, d1); d1 = fmaf(k3[1], a.y, d1);
            float d2 = fmaf(k0[2], a.z, kc[2]);
            d2 = fmaf(k1[2], a.w, d2); d2 = fmaf(k2[2], a.x, d2); d2 = fmaf(k3[2], a.y, d2);
            a0 += __expf(d0);
            a1 += __expf(d1);
            a2 += __expf(d2);
        }
        part[pid * J + j0 + 0] = a0;
        part[pid * J + j0 + 1] = a1;
        part[pid * J + j0 + 2] = a2;
    }
    __syncthreads();

    if (tid < J) {
        float s = 0.f;
        #pragma unroll
        for (int q = 0; q < 8; ++q) s += part[q * J + tid];
        z[vb * J + tid] = s;
    }
}

// ---------------------------------------------------------------------------
// Kernel 2: stage12(composed conv) + BN1 + l2 + ReLU + fc1-PARTIAL.
// One block per v, 1024 threads.  The fc1 column-slice for this v
// (fc1_w[:, v*25:(v+1)*25]) is applied to this block's x_v[p,b] and
// accumulated into global acc[n,b] via coalesced atomicAdd (pure
// reduction, no fences, no ordering protocol).  xT never hits global.
// LDS ~131 KB, 1 block/CU.
// ---------------------------------------------------------------------------
__global__ __launch_bounds__(1024) void stage2_kernel(
    const float* __restrict__ z,               // [V*B, J]
    const float* __restrict__ w1,              // [V, NF, 3]
    const float* __restrict__ w2,              // [V, 8, NF]
    const float* __restrict__ l1_w,            // [V, S2, J]
    const float* __restrict__ l1_b,            // [V, S2]
    const float* __restrict__ bn1_g,
    const float* __restrict__ bn1_b,
    const float* __restrict__ l2_w,            // [V, S2, S2]
    const float* __restrict__ l2_b,            // [V, S2]
    const float* __restrict__ fc1_w,           // [N1, V*S2]
    float* __restrict__ acc_out)               // [N1, B] += partials
{
    const int v   = blockIdx.x;
    const int tid = threadIdx.x;
    const int vm  = (v + V - 1) & (V - 1);
    const int vp  = (v + 1) & (V - 1);

    __shared__ float wcomb[8][3];
    __shared__ float l1ws[S2 * J];
    __shared__ float l1bs[S2];
    __shared__ float wl2[S2 * S2];
    __shared__ float l2bs[S2];
    __shared__ float hs[B * J];                // 38.4 KB
    __shared__ float us[B * S2];               // 12.8 KB
    __shared__ float xs[S2 * B];               // 12.8 KB  x_v[p][b]
    __shared__ float fw[N1 * S2];              // 50 KB    fc1 slice [n][p]
    __shared__ float sred[32 * S2], ssred[32 * S2];
    __shared__ float sc[S2], sh[S2];

    // ---- stage weights ----
    if (tid < 24) {
        int g = tid / 3, c = tid - g * 3;
        const float* w2r = w2 + v * 8 * NF + g * NF;
        const float* w1c = w1 + v * NF * 3 + c;
        float s = 0.f;
        #pragma unroll
        for (int f = 0; f < NF; ++f) s += w2r[f] * w1c[f * 3];
        wcomb[g][c] = s;
    }
    for (int i = tid; i < S2 * J;  i += 1024) l1ws[i] = l1_w[v * S2 * J + i];
    for (int i = tid; i < S2 * S2; i += 1024) wl2[i]  = l2_w[v * S2 * S2 + i];
    for (int i = tid; i < N1 * S2; i += 1024) {
        int nn = i / S2, p = i - nn * S2;
        fw[i] = fc1_w[nn * (V * S2) + v * S2 + p];
    }
    if (tid < S2) { l1bs[tid] = l1_b[v * S2 + tid]; l2bs[tid] = l2_b[v * S2 + tid]; }
    __syncthreads();

    // ---- composed conv + max8 ----
    for (int t = tid; t < B * J; t += 1024) {
        float a0 = z[vm * (B * J) + t];
        float a1 = z[v  * (B * J) + t];
        float a2 = z[vp * (B * J) + t];
        float hm = -3.4e38f;
        #pragma unroll
        for (int g = 0; g < 8; ++g) {
            float s = wcomb[g][0] * a0 + wcomb[g][1] * a1 + wcomb[g][2] * a2;
            hm = fmaxf(hm, s);
        }
        hs[t] = hm;
    }
    __syncthreads();

    // ---- l1 ----
    for (int t = tid; t < S2 * B; t += 1024) {
        int o = t >> 7;
        int b = t & 127;
        float acc = l1bs[o];
        const float* hrow = hs + b * J;
        const float* wrow = l1ws + o * J;
        #pragma unroll 5
        for (int j = 0; j < J; ++j) acc += hrow[j] * wrow[j];
        us[b * S2 + o] = acc;
    }
    __syncthreads();

    // ---- BN1 stats over batch ----
    if (tid < 32 * S2) {
        int c = tid / S2;
        int o = tid - c * S2;
        float s = 0.f, ss = 0.f;
        #pragma unroll
        for (int b = c * 4; b < c * 4 + 4; ++b) {
            float x = us[b * S2 + o];
            s += x; ss += x * x;
        }
        sred[tid] = s; ssred[tid] = ss;
    }
    __syncthreads();

    if (tid < S2) {
        float s = 0.f, ss = 0.f;
        #pragma unroll
        for (int c = 0; c < 32; ++c) { s += sred[c * S2 + tid]; ss += ssred[c * S2 + tid]; }
        float mean = s * (1.f / B);
        float var  = ss * (1.f / B) - mean * mean;
        float istd = rsqrtf(var + 1e-5f);
        float g  = bn1_g[v * S2 + tid];
        float be = bn1_b[v * S2 + tid];
        sc[tid] = g * istd;
        sh[tid] = be - mean * g * istd;
    }
    __syncthreads();

    for (int i = tid; i < B * S2; i += 1024) {
        int o = i % S2;
        us[i] = us[i] * sc[o] + sh[o];
    }
    __syncthreads();

    // ---- l2 + ReLU -> xs[p][b] (LDS only) ----
    for (int t = tid; t < S2 * B; t += 1024) {
        int p = t >> 7;
        int b = t & 127;
        float acc = l2bs[p];
        const float* urow = us + b * S2;
        const float* wrow = wl2 + p * S2;
        #pragma unroll
        for (int o = 0; o < S2; ++o) acc += urow[o] * wrow[o];
        xs[p * B + b] = fmaxf(acc, 0.f);
    }
    __syncthreads();

    // ---- fc1 partial: acc[n,b] += fw[n,:] . xs[:,b] (coalesced atomics) ---
    for (int t = tid; t < N1 * B; t += 1024) {
        int nn = t >> 7;
        int b  = t & 127;
        const float* fr = fw + nn * S2;
        const float* xc = xs + b;
        float s = 0.f;
        #pragma unroll
        for (int p = 0; p < S2; ++p) s += fr[p] * xc[p * B];
        atomicAdd(&acc_out[nn * B + b], s);
    }
}

// ---------------------------------------------------------------------------
// Kernel 3: bn2 + fc2.  100 blocks x 2 output neurons, 256 threads.
// Each block redundantly computes BN2 stats over acc+fc1_b (L2/L3-hot),
// then the two fc2 dot products sharing one pass over y.
// ---------------------------------------------------------------------------
__global__ __launch_bounds__(256) void bn2_fc2_kernel(
    const float* __restrict__ acc_in,          // [N1, B]
    const float* __restrict__ fc1_b,           // [N1]
    const float* __restrict__ bn2_g,
    const float* __restrict__ bn2_b,
    const float* __restrict__ fc2_w,           // [200, N1]
    const float* __restrict__ fc2_b,           // [200]
    float* __restrict__ out)                   // [B, 200]
{
    const int k0  = blockIdx.x * 2;
    const int tid = threadIdx.x;

    __shared__ float w0s[N1], w1s[N1];
    __shared__ float fbs[N1];
    __shared__ float sred[2 * N1], ssred[2 * N1];
    __shared__ float scl[N1], shs[N1];
    __shared__ float pr0[B], pr1[B];

    for (int i = tid; i < N1; i += 256) {
        w0s[i] = fc2_w[k0 * N1 + i];
        w1s[i] = fc2_w[(k0 + 1) * N1 + i];
        fbs[i] = fc1_b[i];
    }
    __syncthreads();

    // stats: (n, half-of-batch) tasks
    for (int idx = tid; idx < 2 * N1; idx += 256) {
        int nn = idx >> 1;
        int c  = idx & 1;
        const float* ap = acc_in + nn * B + c * 64;
        float fb = fbs[nn];
        float s = 0.f, ss = 0.f;
        #pragma unroll 8
        for (int j = 0; j < 64; ++j) {
            float x = ap[j] + fb;
            s += x; ss += x * x;
        }
        sred[idx] = s; ssred[idx] = ss;
    }
    __syncthreads();

    for (int nn = tid; nn < N1; nn += 256) {
        float s  = sred[2 * nn] + sred[2 * nn + 1];
        float ss = ssred[2 * nn] + ssred[2 * nn + 1];
        float mean = s * (1.f / B);
        float var  = ss * (1.f / B) - mean * mean;
        float istd = rsqrtf(var + 1e-5f);
        float g  = bn2_g[nn];
        float be = bn2_b[nn];
        scl[nn] = g * istd;
        shs[nn] = be - mean * g * istd;
    }
    __syncthreads();

    // fc2: 2 halves of K=500, 2 neurons sharing each y
    const int kk = tid >> 7;
    const int b  = tid & 127;
    float a0 = 0.f, a1 = 0.f;
    for (int nn = kk * 250; nn < kk * 250 + 250; ++nn) {
        float y = (acc_in[nn * B + b] + fbs[nn]) * scl[nn] + shs[nn];
        a0 += y * w0s[nn];
        a1 += y * w1s[nn];
    }
    if (kk == 1) { pr0[b] = a0; pr1[b] = a1; }
    __syncthreads();

    if (kk == 0) {
        out[b * 200 + k0]     = a0 + pr0[b] + fc2_b[k0];
        out[b * 200 + k0 + 1] = a1 + pr1[b] + fc2_b[k0 + 1];
    }
}

// ---------------------------------------------------------------------------
extern "C" void kernel_launch(void* const* d_in, const int* in_sizes, int n_in,
                              void* d_out, int out_size, void* d_ws, size_t ws_size,
                              hipStream_t stream) {
    const float* births    = (const float*)d_in[0];
    const float* lifetimes = (const float*)d_in[1];
    const int*   mask      = (const int*)d_in[2];
    const float* centers   = (const float*)d_in[3];
    const float* sharpness = (const float*)d_in[4];
    const float* w1        = (const float*)d_in[5];
    const float* w2        = (const float*)d_in[6];
    const float* l1_w      = (const float*)d_in[7];
    const float* l1_b      = (const float*)d_in[8];
    const float* bn1_g     = (const float*)d_in[9];
    const float* bn1_b     = (const float*)d_in[10];
    const float* l2_w      = (const float*)d_in[11];
    const float* l2_b      = (const float*)d_in[12];
    const float* fc1_w     = (const float*)d_in[13];
    const float* fc1_b     = (const float*)d_in[14];
    const float* bn2_g     = (const float*)d_in[15];
    const float* bn2_b     = (const float*)d_in[16];
    const float* fc2_w     = (const float*)d_in[17];
    const float* fc2_b     = (const float*)d_in[18];
    float* out = (float*)d_out;

    float* ws  = (float*)d_ws;
    float* z   = ws;                           // V*B*J = 307200
    float* acc = ws + 307200;                  // N1*B  = 64000

    slayer_kernel <<<V * B, 256, 0, stream>>>(births, lifetimes, mask, centers,
                                              sharpness, z, acc);
    stage2_kernel <<<V, 1024, 0, stream>>>(z, w1, w2, l1_w, l1_b, bn1_g, bn1_b,
                                           l2_w, l2_b, fc1_w, acc);
    bn2_fc2_kernel<<<100, 256, 0, stream>>>(acc, fc1_b, bn2_g, bn2_b,
                                            fc2_w, fc2_b, out);
}

// Round 9
// 154.628 us; speedup vs baseline: 1.1186x; 1.1186x over previous
//
#include <hip/hip_runtime.h>

#define V 32
#define B 128
#define P 256
#define J 75
#define NF 32
#define S2 25
#define N1 500

// ---------------------------------------------------------------------------
// Kernel 1: transform + SLayer.  Phase 2 register-tiled: 8 point-parts x
// 25 threads x 3 centers -> each 16B LDS read feeds 12 FMA + 3 exp.
// ---------------------------------------------------------------------------
__global__ __launch_bounds__(256) void slayer_kernel(
    const float* __restrict__ births,
    const float* __restrict__ lifetimes,
    const int* __restrict__ mask,
    const float* __restrict__ centers,
    const float* __restrict__ sharpness,
    float* __restrict__ z)                     // [V*B, J]
{
    const int vb = blockIdx.x;                 // v*B + b
    const int v  = vb >> 7;
    const int tid = threadIdx.x;
    const int lane = tid & 63;

    __shared__ float4 pts[P];
    __shared__ int cnt;
    __shared__ float part[8 * J];

    if (tid == 0) cnt = 0;
    __syncthreads();

    const float inv = 0.70710678118654752f;
    {
        const int gi = vb * P + tid;
        float b0 = births[gi];
        float l0 = lifetimes[gi];
        int   m  = mask[gi];
        float d  = b0 + l0 + 0.01f;
        float x  = (b0 + d) * inv;
        float y  = (d - b0) * inv;
        if (y <= 0.1f) y = __logf(y * 10.0f) * 0.1f + 0.1f;

        bool keep = (m != 0);
        unsigned long long bal = __ballot(keep);
        unsigned long long lt  = (1ull << lane) - 1ull;
        int prefix = __popcll(bal & lt);
        int total  = __popcll(bal);
        int base = 0;
        if (lane == 0) base = atomicAdd(&cnt, total);
        base = __shfl(base, 0, 64);
        if (keep) pts[base + prefix] = make_float4(x, y, x * x, y * y);
    }
    __syncthreads();

    const int n = cnt;
    const int pid = tid >> 5;                  // 0..7 point-part
    const int t32 = tid & 31;
    if (t32 < 25) {
        const int j0 = t32 * 3;                // 3 centers per thread
        float k0[3], k1[3], k2[3], k3[3], kc[3];
        #pragma unroll
        for (int c = 0; c < 3; ++c) {
            const int cj = (v * J + j0 + c) * 2;
            float cx = centers[cj + 0];
            float cy = centers[cj + 1];
            float sx = sharpness[cj + 0];
            float sy = sharpness[cj + 1];
            float s2x = sx * sx, s2y = sy * sy;
            k0[c] = -s2x;
            k1[c] = -s2y;
            k2[c] = 2.0f * s2x * cx;
            k3[c] = 2.0f * s2y * cy;
            kc[c] = -(s2x * cx * cx + s2y * cy * cy);
        }
        float a0 = 0.f, a1 = 0.f, a2 = 0.f;
        const int p0 = (n * pid) >> 3;
        const int p1 = (n * (pid + 1)) >> 3;
        #pragma unroll 2
        for (int p = p0; p < p1; ++p) {
            float4 a = pts[p];
            float d0 = fmaf(k0[0], a.z, kc[0]);
            d0 = fmaf(k1[0], a.w, d0); d0 = fmaf(k2[0], a.x, d0); d0 = fmaf(k3[0], a.y, d0);
            float d1 = fmaf(k0[1], a.z, kc[1]);
            d1 = fmaf(k1[1], a.w, d1); d1 = fmaf(k2[1], a.x, d1); d1 = fmaf(k3[1], a.y, d1);
            float d2 = fmaf(k0[2], a.z, kc[2]);
            d2 = fmaf(k1[2], a.w, d2); d2 = fmaf(k2[2], a.x, d2); d2 = fmaf(k3[2], a.y, d2);
            a0 += __expf(d0);
            a1 += __expf(d1);
            a2 += __expf(d2);
        }
        part[pid * J + j0 + 0] = a0;
        part[pid * J + j0 + 1] = a1;
        part[pid * J + j0 + 2] = a2;
    }
    __syncthreads();

    if (tid < J) {
        float s = 0.f;
        #pragma unroll
        for (int q = 0; q < 8; ++q) s += part[q * J + tid];
        z[vb * J + tid] = s;
    }
}

// ---------------------------------------------------------------------------
// Kernel 2: stage12(composed conv) + BN1 + l2 + ReLU -> xT.  (round-7
// verified: one block per v, 1024 threads, fence-free, NO fc1 work here.)
// ---------------------------------------------------------------------------
__global__ __launch_bounds__(1024) void stage2_kernel(
    const float* __restrict__ z,               // [V*B, J]
    const float* __restrict__ w1,              // [V, NF, 3]
    const float* __restrict__ w2,              // [V, 8, NF]
    const float* __restrict__ l1_w,            // [V, S2, J]
    const float* __restrict__ l1_b,            // [V, S2]
    const float* __restrict__ bn1_g,
    const float* __restrict__ bn1_b,
    const float* __restrict__ l2_w,            // [V, S2, S2]
    const float* __restrict__ l2_b,            // [V, S2]
    float* __restrict__ xT)                    // [V*S2, B]
{
    const int v   = blockIdx.x;
    const int tid = threadIdx.x;
    const int vm  = (v + V - 1) & (V - 1);
    const int vp  = (v + 1) & (V - 1);

    __shared__ float wcomb[8][3];
    __shared__ float l1ws[S2 * J];
    __shared__ float l1bs[S2];
    __shared__ float wl2[S2 * S2];
    __shared__ float l2bs[S2];
    __shared__ float hs[B * J];                // 38.4 KB
    __shared__ float us[B * S2];               // 12.8 KB
    __shared__ float sred[32 * S2], ssred[32 * S2];
    __shared__ float sc[S2], sh[S2];

    if (tid < 24) {
        int g = tid / 3, c = tid - g * 3;
        const float* w2r = w2 + v * 8 * NF + g * NF;
        const float* w1c = w1 + v * NF * 3 + c;
        float s = 0.f;
        #pragma unroll
        for (int f = 0; f < NF; ++f) s += w2r[f] * w1c[f * 3];
        wcomb[g][c] = s;
    }
    for (int i = tid; i < S2 * J;  i += 1024) l1ws[i] = l1_w[v * S2 * J + i];
    for (int i = tid; i < S2 * S2; i += 1024) wl2[i]  = l2_w[v * S2 * S2 + i];
    if (tid < S2) { l1bs[tid] = l1_b[v * S2 + tid]; l2bs[tid] = l2_b[v * S2 + tid]; }
    __syncthreads();

    for (int t = tid; t < B * J; t += 1024) {
        float a0 = z[vm * (B * J) + t];
        float a1 = z[v  * (B * J) + t];
        float a2 = z[vp * (B * J) + t];
        float hm = -3.4e38f;
        #pragma unroll
        for (int g = 0; g < 8; ++g) {
            float s = wcomb[g][0] * a0 + wcomb[g][1] * a1 + wcomb[g][2] * a2;
            hm = fmaxf(hm, s);
        }
        hs[t] = hm;
    }
    __syncthreads();

    for (int t = tid; t < S2 * B; t += 1024) {
        int o = t >> 7;
        int b = t & 127;
        float acc = l1bs[o];
        const float* hrow = hs + b * J;
        const float* wrow = l1ws + o * J;
        #pragma unroll 5
        for (int j = 0; j < J; ++j) acc += hrow[j] * wrow[j];
        us[b * S2 + o] = acc;
    }
    __syncthreads();

    if (tid < 32 * S2) {
        int c = tid / S2;
        int o = tid - c * S2;
        float s = 0.f, ss = 0.f;
        #pragma unroll
        for (int b = c * 4; b < c * 4 + 4; ++b) {
            float x = us[b * S2 + o];
            s += x; ss += x * x;
        }
        sred[tid] = s; ssred[tid] = ss;
    }
    __syncthreads();

    if (tid < S2) {
        float s = 0.f, ss = 0.f;
        #pragma unroll
        for (int c = 0; c < 32; ++c) { s += sred[c * S2 + tid]; ss += ssred[c * S2 + tid]; }
        float mean = s * (1.f / B);
        float var  = ss * (1.f / B) - mean * mean;
        float istd = rsqrtf(var + 1e-5f);
        float g  = bn1_g[v * S2 + tid];
        float be = bn1_b[v * S2 + tid];
        sc[tid] = g * istd;
        sh[tid] = be - mean * g * istd;
    }
    __syncthreads();

    for (int i = tid; i < B * S2; i += 1024) {
        int o = i % S2;
        us[i] = us[i] * sc[o] + sh[o];
    }
    __syncthreads();

    for (int t = tid; t < S2 * B; t += 1024) {
        int p = t >> 7;
        int b = t & 127;
        float acc = l2bs[p];
        const float* urow = us + b * S2;
        const float* wrow = wl2 + p * S2;
        #pragma unroll
        for (int o = 0; o < S2; ++o) acc += urow[o] * wrow[o];
        acc = fmaxf(acc, 0.f);
        xT[(v * S2 + p) * B + b] = acc;
    }
}

// ---------------------------------------------------------------------------
// Kernel 3: fc1 + BN over batch.  2 neurons per block (250 blocks), 256
// threads = (kk half of K, b).  Halves xT L2 re-read vs 1 neuron/block.
// ---------------------------------------------------------------------------
__global__ __launch_bounds__(256) void fc1_bn2_kernel(
    const float* __restrict__ xT,              // [800, B]
    const float* __restrict__ fc1_w,           // [500, 800]
    const float* __restrict__ fc1_b,           // [500]
    const float* __restrict__ bn2_g,
    const float* __restrict__ bn2_b,
    float* __restrict__ y1n)                   // [500, B]
{
    const int n0  = blockIdx.x * 2;
    const int tid = threadIdx.x;
    const int kk  = tid >> 7;                  // 0/1: K half
    const int b   = tid & 127;
    const int K   = V * S2;                    // 800

    __shared__ float wsm[2][V * S2];
    __shared__ float pr0[B], pr1[B];
    __shared__ float red[2][2][2];             // [wave][stat][neuron]

    for (int i = tid; i < 2 * K; i += 256) {
        int ni = i / K;
        int k  = i - ni * K;
        wsm[ni][k] = fc1_w[(n0 + ni) * K + k];
    }
    __syncthreads();

    float a0 = 0.f, a1 = 0.f;
    {
        const float* xp = xT + kk * 400 * B + b;
        const float* w0 = wsm[0] + kk * 400;
        const float* w1p = wsm[1] + kk * 400;
        for (int k = 0; k < 400; ++k) {
            float xv = xp[k * B];
            a0 += xv * w0[k];
            a1 += xv * w1p[k];
        }
    }

    if (kk == 1) { pr0[b] = a0; pr1[b] = a1; }
    __syncthreads();

    float t0 = 0.f, t1 = 0.f;
    if (kk == 0) {
        t0 = a0 + pr0[b] + fc1_b[n0];
        t1 = a1 + pr1[b] + fc1_b[n0 + 1];
        const int wave = tid >> 6;             // 0/1
        const int lane = tid & 63;
        float s0 = t0, q0 = t0 * t0;
        float s1 = t1, q1 = t1 * t1;
        #pragma unroll
        for (int off = 32; off > 0; off >>= 1) {
            s0 += __shfl_down(s0, off, 64);
            q0 += __shfl_down(q0, off, 64);
            s1 += __shfl_down(s1, off, 64);
            q1 += __shfl_down(q1, off, 64);
        }
        if (lane == 0) {
            red[wave][0][0] = s0; red[wave][1][0] = q0;
            red[wave][0][1] = s1; red[wave][1][1] = q1;
        }
    }
    __syncthreads();

    if (kk == 0) {
        #pragma unroll
        for (int ni = 0; ni < 2; ++ni) {
            float s  = red[0][0][ni] + red[1][0][ni];
            float ss = red[0][1][ni] + red[1][1][ni];
            float mean = s * (1.f / B);
            float var  = ss * (1.f / B) - mean * mean;
            float istd = rsqrtf(var + 1e-5f);
            float g   = bn2_g[n0 + ni];
            float be  = bn2_b[n0 + ni];
            float scl = g * istd;
            float t   = ni ? t1 : t0;
            y1n[(n0 + ni) * B + b] = t * scl + (be - mean * scl);
        }
    }
}

// ---------------------------------------------------------------------------
// Kernel 4: fc2.  (round-7 verified)
// ---------------------------------------------------------------------------
__global__ __launch_bounds__(256) void fc2_kernel(
    const float* __restrict__ y1n,             // [500, B]
    const float* __restrict__ fc2_w,           // [200, 500]
    const float* __restrict__ fc2_b,           // [200]
    float* __restrict__ out)                   // [B, 200]
{
    const int n2 = blockIdx.x;
    const int tid = threadIdx.x;
    const int kk = tid >> 7;
    const int b  = tid & 127;

    __shared__ float wsm[500];
    __shared__ float pr[B];
    for (int i = tid; i < 500; i += 256) wsm[i] = fc2_w[n2 * 500 + i];
    __syncthreads();

    float acc = 0.f;
    const float* yp = y1n + kk * 250 * B + b;
    const float* wp = wsm + kk * 250;
    for (int k = 0; k < 250; ++k) acc += yp[k * B] * wp[k];

    if (kk == 1) pr[b] = acc;
    __syncthreads();

    if (kk == 0)
        out[b * 200 + n2] = acc + pr[b] + fc2_b[n2];
}

// ---------------------------------------------------------------------------
extern "C" void kernel_launch(void* const* d_in, const int* in_sizes, int n_in,
                              void* d_out, int out_size, void* d_ws, size_t ws_size,
                              hipStream_t stream) {
    const float* births    = (const float*)d_in[0];
    const float* lifetimes = (const float*)d_in[1];
    const int*   mask      = (const int*)d_in[2];
    const float* centers   = (const float*)d_in[3];
    const float* sharpness = (const float*)d_in[4];
    const float* w1        = (const float*)d_in[5];
    const float* w2        = (const float*)d_in[6];
    const float* l1_w      = (const float*)d_in[7];
    const float* l1_b      = (const float*)d_in[8];
    const float* bn1_g     = (const float*)d_in[9];
    const float* bn1_b     = (const float*)d_in[10];
    const float* l2_w      = (const float*)d_in[11];
    const float* l2_b      = (const float*)d_in[12];
    const float* fc1_w     = (const float*)d_in[13];
    const float* fc1_b     = (const float*)d_in[14];
    const float* bn2_g     = (const float*)d_in[15];
    const float* bn2_b     = (const float*)d_in[16];
    const float* fc2_w     = (const float*)d_in[17];
    const float* fc2_b     = (const float*)d_in[18];
    float* out = (float*)d_out;

    float* ws  = (float*)d_ws;
    float* z   = ws;                           // V*B*J = 307200
    float* xT  = ws + 307200;                  // 800*B = 102400
    float* y1n = ws + 307200 + 102400;         // 500*B = 64000

    slayer_kernel <<<V * B, 256, 0, stream>>>(births, lifetimes, mask, centers,
                                              sharpness, z);
    stage2_kernel <<<V, 1024, 0, stream>>>(z, w1, w2, l1_w, l1_b, bn1_g, bn1_b,
                                           l2_w, l2_b, xT);
    fc1_bn2_kernel<<<250, 256, 0, stream>>>(xT, fc1_w, fc1_b, bn2_g, bn2_b, y1n);
    fc2_kernel    <<<200, 256, 0, stream>>>(y1n, fc2_w, fc2_b, out);
}

// Round 10
// 147.746 us; speedup vs baseline: 1.1707x; 1.0466x over previous
//
#include <hip/hip_runtime.h>

#define V 32
#define B 128
#define P 256
#define J 75
#define NF 32
#define S2 25

// ---------------------------------------------------------------------------
// Kernel 1: transform + SLayer with mask compaction. (round-3 verified)
// ---------------------------------------------------------------------------
__global__ __launch_bounds__(256) void slayer_kernel(
    const float* __restrict__ births,
    const float* __restrict__ lifetimes,
    const int* __restrict__ mask,
    const float* __restrict__ centers,
    const float* __restrict__ sharpness,
    float* __restrict__ z)                     // [V*B, J]
{
    const int vb = blockIdx.x;                 // v*B + b
    const int v  = vb >> 7;
    const int tid = threadIdx.x;
    const int lane = tid & 63;

    __shared__ float4 pts[P];
    __shared__ int cnt;
    __shared__ float part[2][J];

    if (tid == 0) cnt = 0;
    __syncthreads();

    const float inv = 0.70710678118654752f;
    {
        const int gi = vb * P + tid;
        float b0 = births[gi];
        float l0 = lifetimes[gi];
        int   m  = mask[gi];
        float d  = b0 + l0 + 0.01f;
        float x  = (b0 + d) * inv;
        float y  = (d - b0) * inv;
        if (y <= 0.1f) y = __logf(y * 10.0f) * 0.1f + 0.1f;

        bool keep = (m != 0);
        unsigned long long bal = __ballot(keep);
        unsigned long long lt  = (1ull << lane) - 1ull;
        int prefix = __popcll(bal & lt);
        int total  = __popcll(bal);
        int base = 0;
        if (lane == 0) base = atomicAdd(&cnt, total);
        base = __shfl(base, 0, 64);
        if (keep) pts[base + prefix] = make_float4(x, y, x * x, y * y);
    }
    __syncthreads();

    const int n = cnt;
    float acc = 0.f;
    if (tid < 3 * J) {
        const int pid = tid / J;               // 0,1,2
        const int j   = tid - pid * J;
        const int cj  = (v * J + j) * 2;
        float cx = centers[cj + 0];
        float cy = centers[cj + 1];
        float sx = sharpness[cj + 0];
        float sy = sharpness[cj + 1];
        float s2x = sx * sx, s2y = sy * sy;
        float k0 = -s2x;
        float k1 = -s2y;
        float k2 = 2.0f * s2x * cx;
        float k3 = 2.0f * s2y * cy;
        float kc = -(s2x * cx * cx + s2y * cy * cy);
        const int p0 = (n * pid) / 3;
        const int p1 = (n * (pid + 1)) / 3;
        #pragma unroll 4
        for (int p = p0; p < p1; ++p) {
            float4 a = pts[p];
            float d = fmaf(k0, a.z, kc);
            d = fmaf(k1, a.w, d);
            d = fmaf(k2, a.x, d);
            d = fmaf(k3, a.y, d);
            acc += __expf(d);
        }
        if (pid > 0) part[pid - 1][j] = acc;
    }
    __syncthreads();

    if (tid < J)
        z[vb * J + tid] = acc + part[0][tid] + part[1][tid];
}

// ---------------------------------------------------------------------------
// Kernel 2 (merged, FENCE-FREE): stage12 + BN1 + l2 + ReLU -> xT.
// One block per v, 1024 threads.  BN over batch is a plain LDS reduction.
// conv1/conv2 composed into wcomb[8][3] (no nonlinearity between them).
// ---------------------------------------------------------------------------
__global__ __launch_bounds__(1024) void stage2_kernel(
    const float* __restrict__ z,               // [V*B, J]
    const float* __restrict__ w1,              // [V, NF, 3]
    const float* __restrict__ w2,              // [V, 8, NF]
    const float* __restrict__ l1_w,            // [V, S2, J]
    const float* __restrict__ l1_b,            // [V, S2]
    const float* __restrict__ bn1_g,
    const float* __restrict__ bn1_b,
    const float* __restrict__ l2_w,            // [V, S2, S2]
    const float* __restrict__ l2_b,            // [V, S2]
    float* __restrict__ xT)                    // [V*S2, B]
{
    const int v   = blockIdx.x;
    const int tid = threadIdx.x;
    const int vm  = (v + V - 1) & (V - 1);
    const int vp  = (v + 1) & (V - 1);

    __shared__ float wcomb[8][3];
    __shared__ float l1ws[S2 * J];
    __shared__ float l1bs[S2];
    __shared__ float wl2[S2 * S2];
    __shared__ float l2bs[S2];
    __shared__ float hs[B * J];                // 38.4 KB
    __shared__ float us[B * S2];               // 12.8 KB
    __shared__ float sred[32 * S2], ssred[32 * S2];
    __shared__ float sc[S2], sh[S2];

    if (tid < 24) {
        int g = tid / 3, c = tid - g * 3;
        const float* w2r = w2 + v * 8 * NF + g * NF;
        const float* w1c = w1 + v * NF * 3 + c;
        float s = 0.f;
        #pragma unroll
        for (int f = 0; f < NF; ++f) s += w2r[f] * w1c[f * 3];
        wcomb[g][c] = s;
    }
    for (int i = tid; i < S2 * J;  i += 1024) l1ws[i] = l1_w[v * S2 * J + i];
    for (int i = tid; i < S2 * S2; i += 1024) wl2[i]  = l2_w[v * S2 * S2 + i];
    if (tid < S2) { l1bs[tid] = l1_b[v * S2 + tid]; l2bs[tid] = l2_b[v * S2 + tid]; }
    __syncthreads();

    for (int t = tid; t < B * J; t += 1024) {
        float a0 = z[vm * (B * J) + t];
        float a1 = z[v  * (B * J) + t];
        float a2 = z[vp * (B * J) + t];
        float hm = -3.4e38f;
        #pragma unroll
        for (int g = 0; g < 8; ++g) {
            float s = wcomb[g][0] * a0 + wcomb[g][1] * a1 + wcomb[g][2] * a2;
            hm = fmaxf(hm, s);
        }
        hs[t] = hm;
    }
    __syncthreads();

    for (int t = tid; t < S2 * B; t += 1024) {
        int o = t >> 7;
        int b = t & 127;
        float acc = l1bs[o];
        const float* hrow = hs + b * J;
        const float* wrow = l1ws + o * J;
        #pragma unroll 5
        for (int j = 0; j < J; ++j) acc += hrow[j] * wrow[j];
        us[b * S2 + o] = acc;
    }
    __syncthreads();

    if (tid < 32 * S2) {
        int c = tid / S2;
        int o = tid - c * S2;
        float s = 0.f, ss = 0.f;
        #pragma unroll
        for (int b = c * 4; b < c * 4 + 4; ++b) {
            float x = us[b * S2 + o];
            s += x; ss += x * x;
        }
        sred[tid] = s; ssred[tid] = ss;
    }
    __syncthreads();

    if (tid < S2) {
        float s = 0.f, ss = 0.f;
        #pragma unroll
        for (int c = 0; c < 32; ++c) { s += sred[c * S2 + tid]; ss += ssred[c * S2 + tid]; }
        float mean = s * (1.f / B);
        float var  = ss * (1.f / B) - mean * mean;
        float istd = rsqrtf(var + 1e-5f);
        float g  = bn1_g[v * S2 + tid];
        float be = bn1_b[v * S2 + tid];
        sc[tid] = g * istd;
        sh[tid] = be - mean * g * istd;
    }
    __syncthreads();

    for (int i = tid; i < B * S2; i += 1024) {
        int o = i % S2;
        us[i] = us[i] * sc[o] + sh[o];
    }
    __syncthreads();

    for (int t = tid; t < S2 * B; t += 1024) {
        int p = t >> 7;
        int b = t & 127;
        float acc = l2bs[p];
        const float* urow = us + b * S2;
        const float* wrow = wl2 + p * S2;
        #pragma unroll
        for (int o = 0; o < S2; ++o) acc += urow[o] * wrow[o];
        acc = fmaxf(acc, 0.f);
        xT[(v * S2 + p) * B + b] = acc;
    }
}

// ---------------------------------------------------------------------------
// Kernel 3: fc1 + BN over batch.  One block per neuron (500 blocks),
// 256 threads: K=800 split into two 400-iter halves (kk = tid>>7).
// ---------------------------------------------------------------------------
__global__ __launch_bounds__(256) void fc1_bn2_kernel(
    const float* __restrict__ xT,              // [800, B]
    const float* __restrict__ fc1_w,           // [500, 800]
    const float* __restrict__ fc1_b,           // [500]
    const float* __restrict__ bn2_g,
    const float* __restrict__ bn2_b,
    float* __restrict__ y1n)                   // [500, B]
{
    const int n  = blockIdx.x;                 // neuron
    const int tid = threadIdx.x;
    const int kk = tid >> 7;                   // 0/1: K half
    const int b  = tid & 127;
    const int K  = V * S2;                     // 800

    __shared__ float wsm[V * S2];
    __shared__ float pr[B];
    __shared__ float red[2][2];

    for (int i = tid; i < K; i += 256) wsm[i] = fc1_w[n * K + i];
    __syncthreads();

    float acc = 0.f;
    const float* xp = xT + kk * 400 * B + b;
    const float* wp = wsm + kk * 400;
    for (int k = 0; k < 400; ++k) acc += xp[k * B] * wp[k];

    if (kk == 1) pr[b] = acc;
    __syncthreads();

    float t = 0.f;
    if (kk == 0) {
        t = acc + pr[b] + fc1_b[n];
        const int wave = tid >> 6;             // 0/1
        const int lane = tid & 63;
        float s = t, ss = t * t;
        #pragma unroll
        for (int off = 32; off > 0; off >>= 1) {
            s  += __shfl_down(s,  off, 64);
            ss += __shfl_down(ss, off, 64);
        }
        if (lane == 0) { red[wave][0] = s; red[wave][1] = ss; }
    }
    __syncthreads();

    if (kk == 0) {
        float s  = red[0][0] + red[1][0];
        float ss = red[0][1] + red[1][1];
        float mean = s * (1.f / B);
        float var  = ss * (1.f / B) - mean * mean;
        float istd = rsqrtf(var + 1e-5f);
        float g   = bn2_g[n];
        float be  = bn2_b[n];
        float scl = g * istd;
        y1n[n * B + b] = t * scl + (be - mean * scl);
    }
}

// ---------------------------------------------------------------------------
// Kernel 4: fc2.  (round-7 verified)
// ---------------------------------------------------------------------------
__global__ __launch_bounds__(256) void fc2_kernel(
    const float* __restrict__ y1n,             // [500, B]
    const float* __restrict__ fc2_w,           // [200, 500]
    const float* __restrict__ fc2_b,           // [200]
    float* __restrict__ out)                   // [B, 200]
{
    const int n2 = blockIdx.x;
    const int tid = threadIdx.x;
    const int kk = tid >> 7;
    const int b  = tid & 127;

    __shared__ float wsm[500];
    __shared__ float pr[B];
    for (int i = tid; i < 500; i += 256) wsm[i] = fc2_w[n2 * 500 + i];
    __syncthreads();

    float acc = 0.f;
    const float* yp = y1n + kk * 250 * B + b;
    const float* wp = wsm + kk * 250;
    for (int k = 0; k < 250; ++k) acc += yp[k * B] * wp[k];

    if (kk == 1) pr[b] = acc;
    __syncthreads();

    if (kk == 0)
        out[b * 200 + n2] = acc + pr[b] + fc2_b[n2];
}

// ---------------------------------------------------------------------------
extern "C" void kernel_launch(void* const* d_in, const int* in_sizes, int n_in,
                              void* d_out, int out_size, void* d_ws, size_t ws_size,
                              hipStream_t stream) {
    const float* births    = (const float*)d_in[0];
    const float* lifetimes = (const float*)d_in[1];
    const int*   mask      = (const int*)d_in[2];
    const float* centers   = (const float*)d_in[3];
    const float* sharpness = (const float*)d_in[4];
    const float* w1        = (const float*)d_in[5];
    const float* w2        = (const float*)d_in[6];
    const float* l1_w      = (const float*)d_in[7];
    const float* l1_b      = (const float*)d_in[8];
    const float* bn1_g     = (const float*)d_in[9];
    const float* bn1_b     = (const float*)d_in[10];
    const float* l2_w      = (const float*)d_in[11];
    const float* l2_b      = (const float*)d_in[12];
    const float* fc1_w     = (const float*)d_in[13];
    const float* fc1_b     = (const float*)d_in[14];
    const float* bn2_g     = (const float*)d_in[15];
    const float* bn2_b     = (const float*)d_in[16];
    const float* fc2_w     = (const float*)d_in[17];
    const float* fc2_b     = (const float*)d_in[18];
    float* out = (float*)d_out;

    float* ws  = (float*)d_ws;
    float* z   = ws;                           // V*B*J = 307200
    float* xT  = ws + 307200;                  // 800*B = 102400
    float* y1n = ws + 307200 + 102400;         // 500*B = 64000

    slayer_kernel <<<V * B, 256, 0, stream>>>(births, lifetimes, mask, centers, sharpness, z);
    stage2_kernel <<<V, 1024, 0, stream>>>(z, w1, w2, l1_w, l1_b, bn1_g, bn1_b,
                                           l2_w, l2_b, xT);
    fc1_bn2_kernel<<<500, 256, 0, stream>>>(xT, fc1_w, fc1_b, bn2_g, bn2_b, y1n);
    fc2_kernel    <<<200, 256, 0, stream>>>(y1n, fc2_w, fc2_b, out);
}